// Round 6
// baseline (204.806 us; speedup 1.0000x reference)
//
#include <hip/hip_runtime.h>
#include <hip/hip_bf16.h>
#include <math.h>

typedef __attribute__((ext_vector_type(8))) short short8;
typedef __attribute__((ext_vector_type(4))) float f32x4;

#define MFMA_BF16 __builtin_amdgcn_mfma_f32_16x16x32_bf16

static constexpr int Dm = 1024;
static constexpr int Tm = 2048;
static constexpr int Bb = 4;
static constexpr int NHm = 16;
static constexpr int HDm = 64;
static constexpr int Mtot = Bb * Tm;   // 8192
static constexpr int NKT = Tm / 64;    // 32 KV tiles per (b,h)
static constexpr float kQScale = 0.125f * 1.4426950408889634f;  // 1/sqrt(64) * log2(e)

__device__ __forceinline__ unsigned short f2bf(float f) {
  unsigned int u = __float_as_uint(f);
  u += 0x7FFFu + ((u >> 16) & 1u);  // RNE
  return (unsigned short)(u >> 16);
}

__device__ __forceinline__ float fexp2(float x) {  // raw v_exp_f32 (2^x)
  float r;
  asm("v_exp_f32 %0, %1" : "=v"(r) : "v"(x));
  return r;
}

__device__ __forceinline__ void gload16(const void* g, void* l) {
  __builtin_amdgcn_global_load_lds((const __attribute__((address_space(1))) void*)g,
                                   (__attribute__((address_space(3))) void*)l, 16, 0, 0);
}

__global__ __launch_bounds__(256) void cvt_kernel(const float* __restrict__ src,
                                                  short* __restrict__ dst, int n) {
  int stride = gridDim.x * blockDim.x;
  for (int i = blockIdx.x * blockDim.x + threadIdx.x; i * 4 < n; i += stride) {
    float4 v = reinterpret_cast<const float4*>(src)[i];
    short4 o;
    o.x = (short)f2bf(v.x);
    o.y = (short)f2bf(v.y);
    o.z = (short)f2bf(v.z);
    o.w = (short)f2bf(v.w);
    reinterpret_cast<short4*>(dst)[i] = o;
  }
}

// fused fp32->bf16 + transpose: Wt[n][k] = W[k][n], for all four weights
__global__ __launch_bounds__(256) void cvt_t_kernel(
    const float* __restrict__ W0, const float* __restrict__ W1,
    const float* __restrict__ W2, const float* __restrict__ W3,
    short* __restrict__ T0, short* __restrict__ T1,
    short* __restrict__ T2, short* __restrict__ T3) {
  const float* W = blockIdx.z == 0 ? W0 : blockIdx.z == 1 ? W1 : blockIdx.z == 2 ? W2 : W3;
  short* Wt = blockIdx.z == 0 ? T0 : blockIdx.z == 1 ? T1 : blockIdx.z == 2 ? T2 : T3;
  __shared__ __align__(16) short T[64 * 72];
  const int tid = threadIdx.x;
  const int k0 = blockIdx.y * 64, n0 = blockIdx.x * 64;
#pragma unroll
  for (int p = 0; p < 4; ++p) {
    int idx = tid + p * 256;
    int kr = idx >> 4, c4 = (idx & 15) * 4;
    float4 v = *reinterpret_cast<const float4*>(W + (size_t)(k0 + kr) * Dm + n0 + c4);
    T[(c4 + 0) * 72 + kr] = (short)f2bf(v.x);
    T[(c4 + 1) * 72 + kr] = (short)f2bf(v.y);
    T[(c4 + 2) * 72 + kr] = (short)f2bf(v.z);
    T[(c4 + 3) * 72 + kr] = (short)f2bf(v.w);
  }
  __syncthreads();
#pragma unroll
  for (int p = 0; p < 2; ++p) {
    int idx = tid + p * 256;
    int nr = idx >> 3, c8 = (idx & 7) * 8;
    *reinterpret_cast<short8*>(Wt + (size_t)(n0 + nr) * Dm + k0 + c8) =
        *reinterpret_cast<const short8*>(&T[nr * 72 + c8]);
  }
}

// Pipelined 128x128/BK=32 mainloop: 3 LDS buffers, 2-deep prefetch, counted
// vmcnt (4 loads/thread/K-step; never drains fresh prefetch mid-loop).
// LDS chunk-swizzle: LDS(r, c16) holds global chunk c16 ^ ((r>>1)&3), applied
// on the global SOURCE address (global_load_lds writes linearly, rule #21);
// reads use chunk g ^ ((lr>>1)&3) -> quarter-wave spreads 8 banks x 2 = free.
__device__ __forceinline__ void gemm_mainloop(
    const short* __restrict__ A, const short* __restrict__ B,
    int m0, int n0, short* As, short* Bs, f32x4 acc[4][4], int tid) {
  const int lane = tid & 63;
  const int w = tid >> 6;
  const int wr = (w >> 1) * 64, wc = (w & 1) * 64;
  const int lr = lane & 15;
  const int g = lane >> 4;
  const int rowt = tid >> 2;
  const int csw = ((tid & 3) ^ ((tid >> 3) & 3)) * 8;  // pre-swizzled src chunk

  auto stage = [&](int kt, int buf) {
#pragma unroll
    for (int p = 0; p < 2; ++p) {
      gload16(A + (size_t)(m0 + p * 64 + rowt) * Dm + kt * 32 + csw,
              &As[buf * 4096 + (p * 64 + w * 16) * 32]);
      gload16(B + (size_t)(n0 + p * 64 + rowt) * Dm + kt * 32 + csw,
              &Bs[buf * 4096 + (p * 64 + w * 16) * 32]);
    }
  };

  stage(0, 0);
  stage(1, 1);
  const int rsw = (lr >> 1) & 3;
  const int ca = (0 ^ rsw) * 8, cb = (1 ^ rsw) * 8, cc = (2 ^ rsw) * 8, cd = (3 ^ rsw) * 8;
  const int csel = g == 0 ? ca : g == 1 ? cb : g == 2 ? cc : cd;
  for (int kt = 0; kt < Dm / 32; ++kt) {
    if (kt < Dm / 32 - 1) asm volatile("s_waitcnt vmcnt(4)" ::: "memory");
    else                  asm volatile("s_waitcnt vmcnt(0)" ::: "memory");
    __builtin_amdgcn_s_barrier();
    __builtin_amdgcn_sched_barrier(0);
    if (kt + 2 < Dm / 32) stage(kt + 2, (kt + 2) % 3);
    const int cur = kt % 3;
    short8 a[4], b[4];
#pragma unroll
    for (int mi = 0; mi < 4; ++mi)
      a[mi] = *reinterpret_cast<const short8*>(
          &As[cur * 4096 + (wr + mi * 16 + lr) * 32 + csel]);
#pragma unroll
    for (int ni = 0; ni < 4; ++ni)
      b[ni] = *reinterpret_cast<const short8*>(
          &Bs[cur * 4096 + (wc + ni * 16 + lr) * 32 + csel]);
#pragma unroll
    for (int mi = 0; mi < 4; ++mi)
#pragma unroll
      for (int ni = 0; ni < 4; ++ni)
        acc[mi][ni] = MFMA_BF16(a[mi], b[ni], acc[mi][ni], 0, 0, 0);
  }
}

// Fused QKV GEMM. grid = (m=64, n=8, z=3): blocks sharing the X panel (same m)
// share id%8 -> same XCD L2. z=0 Q (scaled), z=1 K LDS-image, z=2 V^T LDS-image.
__global__ __launch_bounds__(256) void gemm_qkv_kernel(
    const short* __restrict__ Ags, const short* __restrict__ Wq,
    const short* __restrict__ Wk, const short* __restrict__ Wv,
    short* __restrict__ Qo, short* __restrict__ Ko, short* __restrict__ Vo) {
  __shared__ __align__(16) short As[3 * 128 * 32];
  __shared__ __align__(16) short Bs[3 * 128 * 32];
  const int z = blockIdx.z;
  const short* Bts = z == 0 ? Wq : z == 1 ? Wk : Wv;
  short* Co = z == 0 ? Qo : z == 1 ? Ko : Vo;
  const int tid = threadIdx.x;
  const int m0 = blockIdx.x * 128;
  const int n0 = blockIdx.y * 128;

  f32x4 acc[4][4];
#pragma unroll
  for (int mi = 0; mi < 4; ++mi)
#pragma unroll
    for (int ni = 0; ni < 4; ++ni)
#pragma unroll
      for (int r = 0; r < 4; ++r) acc[mi][ni][r] = 0.f;

  gemm_mainloop(Ags, Bts, m0, n0, As, Bs, acc, tid);

  const int lane = tid & 63;
  const int w = tid >> 6;
  const int wr = (w >> 1) * 64, wc = (w & 1) * 64;
  const int g = lane >> 4, lr = lane & 15;
#pragma unroll
  for (int mi = 0; mi < 4; ++mi)
#pragma unroll
    for (int ni = 0; ni < 4; ++ni)
#pragma unroll
      for (int r = 0; r < 4; ++r) {
        int mg = m0 + wr + mi * 16 + g * 4 + r;  // C/D: row=(lane>>4)*4+reg
        int ng = n0 + wc + ni * 16 + lr;         // C/D: col=lane&15
        float v = acc[mi][ni][r];
        int b_ = mg >> 11, t_ = mg & 2047, h_ = ng >> 6, d_ = ng & 63;
        size_t bh = (size_t)(b_ * NHm + h_);
        if (z == 0) {
          Co[(bh * Tm + t_) * HDm + d_] = (short)f2bf(v * kQScale);
        } else if (z == 1) {
          Co[((bh * NKT + (t_ >> 6)) << 12) + (t_ & 63) * 64 + (d_ ^ ((t_ & 7) << 3))] =
              (short)f2bf(v);
        } else {
          Co[((bh * NKT + (t_ >> 6)) << 12) + d_ * 64 + ((t_ & 63) ^ ((d_ & 7) << 3))] =
              (short)f2bf(v);
        }
      }
}

// Out-projection: fp32 + bias, row-major. grid = (m=64, n=8).
__global__ __launch_bounds__(256) void gemm_out_kernel(
    const short* __restrict__ Ags, const short* __restrict__ Bts,
    float* __restrict__ Cf, const float* __restrict__ bias) {
  __shared__ __align__(16) short As[3 * 128 * 32];
  __shared__ __align__(16) short Bs[3 * 128 * 32];
  const int tid = threadIdx.x;
  const int m0 = blockIdx.x * 128;
  const int n0 = blockIdx.y * 128;

  f32x4 acc[4][4];
#pragma unroll
  for (int mi = 0; mi < 4; ++mi)
#pragma unroll
    for (int ni = 0; ni < 4; ++ni)
#pragma unroll
      for (int r = 0; r < 4; ++r) acc[mi][ni][r] = 0.f;

  gemm_mainloop(Ags, Bts, m0, n0, As, Bs, acc, tid);

  const int lane = tid & 63;
  const int w = tid >> 6;
  const int wr = (w >> 1) * 64, wc = (w & 1) * 64;
  const int g = lane >> 4, lr = lane & 15;
#pragma unroll
  for (int mi = 0; mi < 4; ++mi)
#pragma unroll
    for (int ni = 0; ni < 4; ++ni)
#pragma unroll
      for (int r = 0; r < 4; ++r) {
        int mg = m0 + wr + mi * 16 + g * 4 + r;
        int ng = n0 + wc + ni * 16 + lr;
        Cf[(size_t)mg * Dm + ng] = acc[mi][ni][r] + bias[ng];
      }
}

// Flash attention, causal, fixed-offset softmax (scores bounded; exp2 safe in
// f32; scale cancels in O=PV/l). Block=(bh, pair): q-tiles pi and 15-pi.
// grid.x = bh so the 8 pair-blocks of one bh share id%8 -> same XCD L2.
// 3-buffer, 2-deep prefetch with counted vmcnt (never 0 mid-loop).
__global__ __launch_bounds__(256) void attn_kernel(
    const short* __restrict__ Qg, const short* __restrict__ Kg,
    const short* __restrict__ Vg, short* __restrict__ Og) {
  __shared__ __align__(16) short Kl[3][64 * 64];
  __shared__ __align__(16) short Vl[3][64 * 64];
  __shared__ __align__(16) short Pl[4][32 * 72];
  const int tid = threadIdx.x;
  const int lane = tid & 63;
  const int w = tid >> 6;
  const int g = lane >> 4;
  const int lr = lane & 15;
  const int bh = blockIdx.x;   // XCD locality: same-bh blocks -> same id%8
  const int pi = blockIdx.y;
  const short* Ks = Kg + ((size_t)bh * NKT << 12);
  const short* Vs = Vg + ((size_t)bh * NKT << 12);
  short* Pw = &Pl[w][0];
  const int b_ = bh >> 4, h_ = bh & 15;

  short8 ones;
#pragma unroll
  for (int j = 0; j < 8; ++j) ones[j] = (short)0x3F80;  // bf16 1.0

  auto stage = [&](int t, int buf) {
#pragma unroll
    for (int i = 0; i < 2; ++i) {
      int ch = w * 2 + i;  // 8 chunks of 1024B per 8KB tile; 4 loads/wave total
      gload16(Ks + ((size_t)t << 12) + ch * 512 + lane * 8, &Kl[buf][ch * 512]);
      gload16(Vs + ((size_t)t << 12) + ch * 512 + lane * 8, &Vl[buf][ch * 512]);
    }
  };

  for (int pass = 0; pass < 2; ++pass) {
    const int qb = pass == 0 ? (15 - pi) : pi;  // heavy pass first
    const int q0 = qb * 128;
    const int qw = q0 + w * 32;
    const short* Qs = Qg + ((size_t)bh * Tm + q0) * HDm;

    short8 qf[2][2];
#pragma unroll
    for (int mi = 0; mi < 2; ++mi)
#pragma unroll
      for (int kk = 0; kk < 2; ++kk)
        qf[mi][kk] = *reinterpret_cast<const short8*>(
            Qs + (w * 32 + mi * 16 + lr) * HDm + kk * 32 + g * 8);

    f32x4 o[2][4], lacc[2];
#pragma unroll
    for (int mi = 0; mi < 2; ++mi)
#pragma unroll
      for (int r = 0; r < 4; ++r) {
        lacc[mi][r] = 0.f;
#pragma unroll
        for (int di = 0; di < 4; ++di) o[mi][di][r] = 0.f;
      }

    const int nt = q0 / 64 + 2;
    stage(0, 0);
    stage(1, 1);
    for (int t = 0; t < nt; ++t) {
      // wait for tile t only; tile t+1's 4 loads stay in flight across barrier
      if (t < nt - 1) asm volatile("s_waitcnt vmcnt(4)" ::: "memory");
      else            asm volatile("s_waitcnt vmcnt(0)" ::: "memory");
      __builtin_amdgcn_s_barrier();
      __builtin_amdgcn_sched_barrier(0);
      if (t + 2 < nt) stage(t + 2, (t + 2) % 3);  // 2 compute phases to land
      const int cur = t % 3;
      const int k0 = t * 64;
      const bool active = (k0 <= qw + 31);
      if (active) {
        // hoisted K fragments (swizzle is an involution on 8-short blocks)
        short8 kf[2][4];
#pragma unroll
        for (int ni = 0; ni < 4; ++ni) {
          int row = ni * 16 + lr;
#pragma unroll
          for (int kk = 0; kk < 2; ++kk)
            kf[kk][ni] = *reinterpret_cast<const short8*>(
                &Kl[cur][row * 64 + ((kk * 32 + g * 8) ^ ((row & 7) << 3))]);
        }
        f32x4 s[2][4];
#pragma unroll
        for (int mi = 0; mi < 2; ++mi)
#pragma unroll
          for (int ni = 0; ni < 4; ++ni) {
            f32x4 acc;
#pragma unroll
            for (int r = 0; r < 4; ++r) acc[r] = 0.f;
            acc = MFMA_BF16(qf[mi][0], kf[0][ni], acc, 0, 0, 0);
            acc = MFMA_BF16(qf[mi][1], kf[1][ni], acc, 0, 0, 0);
            s[mi][ni] = acc;
          }
        if (k0 + 63 > qw) {  // wave-uniform diag branch: apply causal mask
#pragma unroll
          for (int mi = 0; mi < 2; ++mi)
#pragma unroll
            for (int ni = 0; ni < 4; ++ni)
#pragma unroll
              for (int r = 0; r < 4; ++r)
                if (k0 + ni * 16 + lr > qw + mi * 16 + g * 4 + r) s[mi][ni][r] = -1e30f;
        }
        // p = exp2(s); P -> per-wave LDS (XOR-swizzled cols, conflict-free)
#pragma unroll
        for (int mi = 0; mi < 2; ++mi)
#pragma unroll
          for (int ni = 0; ni < 4; ++ni)
#pragma unroll
            for (int r = 0; r < 4; ++r)
              Pw[(mi * 16 + g * 4 + r) * 72 + ((ni * 16 + lr) ^ (g << 4))] =
                  (short)f2bf(fexp2(s[mi][ni][r]));

        // O += P @ V ; l += P @ 1  (V^T in LDS, swizzled cols)
#pragma unroll
        for (int kk = 0; kk < 2; ++kk) {
          short8 pf[2];
#pragma unroll
          for (int mi = 0; mi < 2; ++mi)
            pf[mi] = *reinterpret_cast<const short8*>(
                &Pw[(mi * 16 + lr) * 72 + ((kk * 32 + g * 8) ^ ((lr >> 2) << 4))]);
#pragma unroll
          for (int mi = 0; mi < 2; ++mi)
            lacc[mi] = MFMA_BF16(pf[mi], ones, lacc[mi], 0, 0, 0);
#pragma unroll
          for (int di = 0; di < 4; ++di) {
            int d = di * 16 + lr;
            short8 vf = *reinterpret_cast<const short8*>(
                &Vl[cur][d * 64 + ((kk * 32 + g * 8) ^ ((d & 7) << 3))]);
#pragma unroll
            for (int mi = 0; mi < 2; ++mi)
              o[mi][di] = MFMA_BF16(pf[mi], vf, o[mi][di], 0, 0, 0);
          }
        }
      }
    }
    __syncthreads();  // pass boundary: all reads done before buffers restaged

    // normalize, scatter to (B,T,D) bf16
#pragma unroll
    for (int mi = 0; mi < 2; ++mi)
#pragma unroll
      for (int di = 0; di < 4; ++di)
#pragma unroll
        for (int r = 0; r < 4; ++r) {
          float ov = o[mi][di][r] / lacc[mi][r];
          int qg = q0 + w * 32 + mi * 16 + g * 4 + r;
          int d_ = di * 16 + lr;
          Og[((size_t)b_ * Tm + qg) * Dm + h_ * HDm + d_] = (short)f2bf(ov);
        }
  }
}

extern "C" void kernel_launch(void* const* d_in, const int* in_sizes, int n_in,
                              void* d_out, int out_size, void* d_ws, size_t ws_size,
                              hipStream_t stream) {
  const float* X = (const float*)d_in[0];
  const float* Wq = (const float*)d_in[1];
  const float* Wk = (const float*)d_in[2];
  const float* Wv = (const float*)d_in[3];
  const float* Wo = (const float*)d_in[4];
  const float* bo = (const float*)d_in[5];
  float* out = (float*)d_out;

  char* ws = (char*)d_ws;
  short* Xb = (short*)ws;  ws += (size_t)Mtot * Dm * 2;
  short* Wqt = (short*)ws; ws += (size_t)Dm * Dm * 2;
  short* Wkt = (short*)ws; ws += (size_t)Dm * Dm * 2;
  short* Wvt = (short*)ws; ws += (size_t)Dm * Dm * 2;
  short* Wot = (short*)ws; ws += (size_t)Dm * Dm * 2;
  short* Qb = (short*)ws;  ws += (size_t)Mtot * Dm * 2;
  short* Kb = (short*)ws;  ws += (size_t)Mtot * Dm * 2;
  short* Vb = (short*)ws;  ws += (size_t)Mtot * Dm * 2;
  short* Ab = (short*)ws;  ws += (size_t)Mtot * Dm * 2;

  cvt_kernel<<<dim3(1024), dim3(256), 0, stream>>>(X, Xb, Mtot * Dm);
  cvt_t_kernel<<<dim3(16, 16, 4), dim3(256), 0, stream>>>(Wq, Wk, Wv, Wo, Wqt, Wkt, Wvt, Wot);

  gemm_qkv_kernel<<<dim3(Mtot / 128, Dm / 128, 3), 256, 0, stream>>>(
      Xb, Wqt, Wkt, Wvt, Qb, Kb, Vb);

  attn_kernel<<<dim3(Bb * NHm, 8), 256, 0, stream>>>(Qb, Kb, Vb, Ab);

  gemm_out_kernel<<<dim3(Mtot / 128, Dm / 128), 256, 0, stream>>>(Ab, Wot, out, bo);
}

// Round 7
// 192.806 us; speedup vs baseline: 1.0622x; 1.0622x over previous
//
#include <hip/hip_runtime.h>
#include <hip/hip_bf16.h>
#include <math.h>

typedef __attribute__((ext_vector_type(8))) short short8;
typedef __attribute__((ext_vector_type(4))) float f32x4;

#define MFMA_BF16 __builtin_amdgcn_mfma_f32_16x16x32_bf16

static constexpr int Dm = 1024;
static constexpr int Tm = 2048;
static constexpr int Bb = 4;
static constexpr int NHm = 16;
static constexpr int HDm = 64;
static constexpr int Mtot = Bb * Tm;   // 8192
static constexpr int NKT = Tm / 64;    // 32 KV tiles per (b,h)
static constexpr float kQScale = 0.125f * 1.4426950408889634f;  // 1/sqrt(64) * log2(e)

__device__ __forceinline__ unsigned short f2bf(float f) {
  unsigned int u = __float_as_uint(f);
  u += 0x7FFFu + ((u >> 16) & 1u);  // RNE
  return (unsigned short)(u >> 16);
}

__device__ __forceinline__ float fexp2(float x) {  // raw v_exp_f32 (2^x)
  float r;
  asm("v_exp_f32 %0, %1" : "=v"(r) : "v"(x));
  return r;
}

__device__ __forceinline__ void gload16(const void* g, void* l) {
  __builtin_amdgcn_global_load_lds((const __attribute__((address_space(1))) void*)g,
                                   (__attribute__((address_space(3))) void*)l, 16, 0, 0);
}

__global__ __launch_bounds__(256) void cvt_kernel(const float* __restrict__ src,
                                                  short* __restrict__ dst, int n) {
  int stride = gridDim.x * blockDim.x;
  for (int i = blockIdx.x * blockDim.x + threadIdx.x; i * 4 < n; i += stride) {
    float4 v = reinterpret_cast<const float4*>(src)[i];
    short4 o;
    o.x = (short)f2bf(v.x);
    o.y = (short)f2bf(v.y);
    o.z = (short)f2bf(v.z);
    o.w = (short)f2bf(v.w);
    reinterpret_cast<short4*>(dst)[i] = o;
  }
}

// fused fp32->bf16 + transpose: Wt[n][k] = W[k][n], for all four weights
__global__ __launch_bounds__(256) void cvt_t_kernel(
    const float* __restrict__ W0, const float* __restrict__ W1,
    const float* __restrict__ W2, const float* __restrict__ W3,
    short* __restrict__ T0, short* __restrict__ T1,
    short* __restrict__ T2, short* __restrict__ T3) {
  const float* W = blockIdx.z == 0 ? W0 : blockIdx.z == 1 ? W1 : blockIdx.z == 2 ? W2 : W3;
  short* Wt = blockIdx.z == 0 ? T0 : blockIdx.z == 1 ? T1 : blockIdx.z == 2 ? T2 : T3;
  __shared__ __align__(16) short T[64 * 72];
  const int tid = threadIdx.x;
  const int k0 = blockIdx.y * 64, n0 = blockIdx.x * 64;
#pragma unroll
  for (int p = 0; p < 4; ++p) {
    int idx = tid + p * 256;
    int kr = idx >> 4, c4 = (idx & 15) * 4;
    float4 v = *reinterpret_cast<const float4*>(W + (size_t)(k0 + kr) * Dm + n0 + c4);
    T[(c4 + 0) * 72 + kr] = (short)f2bf(v.x);
    T[(c4 + 1) * 72 + kr] = (short)f2bf(v.y);
    T[(c4 + 2) * 72 + kr] = (short)f2bf(v.z);
    T[(c4 + 3) * 72 + kr] = (short)f2bf(v.w);
  }
  __syncthreads();
#pragma unroll
  for (int p = 0; p < 2; ++p) {
    int idx = tid + p * 256;
    int nr = idx >> 3, c8 = (idx & 7) * 8;
    *reinterpret_cast<short8*>(Wt + (size_t)(n0 + nr) * Dm + k0 + c8) =
        *reinterpret_cast<const short8*>(&T[nr * 72 + c8]);
  }
}

// Minimum-2-phase 128x128/BK=32 mainloop (T3 recipe): 2 LDS buffers (32 KB ->
// 5 blocks/CU). Per K-step: issue next tile's 4 global_load_lds FIRST, then
// ds_read+MFMA current buffer, then ONE __syncthreads (drains the prefetch
// after ~230cy of compute has hidden its latency).
// LDS chunk-swizzle (round-6, verified 0 conflicts): LDS(r,c16) holds global
// chunk c16 ^ ((r>>1)&3), applied on the global SOURCE address (rule #21);
// fragment reads use chunk (g ^ ((lr>>1)&3)) -> 2 lanes/bank = free.
__device__ __forceinline__ void gemm_mainloop2(
    const short* __restrict__ A, const short* __restrict__ B,
    int m0, int n0, short* As, short* Bs, f32x4 acc[4][4], int tid) {
  const int lane = tid & 63;
  const int w = tid >> 6;
  const int wr = (w >> 1) * 64, wc = (w & 1) * 64;
  const int lr = lane & 15;
  const int g = lane >> 4;
  const int rowt = tid >> 2;
  const int csw = ((tid & 3) ^ ((tid >> 3) & 3)) * 8;  // pre-swizzled src chunk

  auto stage = [&](int kt, int buf) {
#pragma unroll
    for (int p = 0; p < 2; ++p) {
      gload16(A + (size_t)(m0 + p * 64 + rowt) * Dm + kt * 32 + csw,
              &As[buf * 4096 + (p * 64 + w * 16) * 32]);
      gload16(B + (size_t)(n0 + p * 64 + rowt) * Dm + kt * 32 + csw,
              &Bs[buf * 4096 + (p * 64 + w * 16) * 32]);
    }
  };

  const int rsw = (lr >> 1) & 3;
  const int csel = (g ^ rsw) * 8;

  stage(0, 0);
  __syncthreads();  // buf0 ready
  for (int kt = 0; kt < Dm / 32; ++kt) {
    if (kt + 1 < Dm / 32) stage(kt + 1, (kt + 1) & 1);  // overlap with compute
    __builtin_amdgcn_sched_barrier(0);  // keep prefetch issues above compute
    const int cur = kt & 1;
    short8 a[4], b[4];
#pragma unroll
    for (int mi = 0; mi < 4; ++mi)
      a[mi] = *reinterpret_cast<const short8*>(
          &As[cur * 4096 + (wr + mi * 16 + lr) * 32 + csel]);
#pragma unroll
    for (int ni = 0; ni < 4; ++ni)
      b[ni] = *reinterpret_cast<const short8*>(
          &Bs[cur * 4096 + (wc + ni * 16 + lr) * 32 + csel]);
#pragma unroll
    for (int mi = 0; mi < 4; ++mi)
#pragma unroll
      for (int ni = 0; ni < 4; ++ni)
        acc[mi][ni] = MFMA_BF16(a[mi], b[ni], acc[mi][ni], 0, 0, 0);
    __syncthreads();  // drains this iter's prefetch; protects buffer swap
  }
}

// Fused QKV as ONE GEMM: A(8192x1024) @ WT3^T, WT3 = [Wq;Wk;Wv]^T contiguous
// [3072][1024]. grid = (m=64, n=24): same-m blocks (share X panel) have
// id%8 == m%8 -> same XCD L2. z = n0>>10 selects output (uniform per block).
__global__ __launch_bounds__(256) void gemm_qkv_kernel(
    const short* __restrict__ Ags, const short* __restrict__ WT3,
    short* __restrict__ Qo, short* __restrict__ Ko, short* __restrict__ Vo) {
  __shared__ __align__(16) short As[2 * 128 * 32];
  __shared__ __align__(16) short Bs[2 * 128 * 32];
  const int tid = threadIdx.x;
  const int m0 = blockIdx.x * 128;
  const int n0g = blockIdx.y * 128;  // 0..3071
  const int z = n0g >> 10;
  const int n0 = n0g & 1023;
  short* Co = z == 0 ? Qo : z == 1 ? Ko : Vo;

  f32x4 acc[4][4];
#pragma unroll
  for (int mi = 0; mi < 4; ++mi)
#pragma unroll
    for (int ni = 0; ni < 4; ++ni)
#pragma unroll
      for (int r = 0; r < 4; ++r) acc[mi][ni][r] = 0.f;

  gemm_mainloop2(Ags, WT3, m0, n0g, As, Bs, acc, tid);

  const int lane = tid & 63;
  const int w = tid >> 6;
  const int wr = (w >> 1) * 64, wc = (w & 1) * 64;
  const int g = lane >> 4, lr = lane & 15;
#pragma unroll
  for (int mi = 0; mi < 4; ++mi)
#pragma unroll
    for (int ni = 0; ni < 4; ++ni)
#pragma unroll
      for (int r = 0; r < 4; ++r) {
        int mg = m0 + wr + mi * 16 + g * 4 + r;  // C/D: row=(lane>>4)*4+reg
        int ng = n0 + wc + ni * 16 + lr;         // C/D: col=lane&15
        float v = acc[mi][ni][r];
        int b_ = mg >> 11, t_ = mg & 2047, h_ = ng >> 6, d_ = ng & 63;
        size_t bh = (size_t)(b_ * NHm + h_);
        if (z == 0) {
          Co[(bh * Tm + t_) * HDm + d_] = (short)f2bf(v * kQScale);
        } else if (z == 1) {
          Co[((bh * NKT + (t_ >> 6)) << 12) + (t_ & 63) * 64 + (d_ ^ ((t_ & 7) << 3))] =
              (short)f2bf(v);
        } else {
          Co[((bh * NKT + (t_ >> 6)) << 12) + d_ * 64 + ((t_ & 63) ^ ((d_ & 7) << 3))] =
              (short)f2bf(v);
        }
      }
}

// Out-projection: fp32 + bias, row-major. grid = (m=64, n=8).
__global__ __launch_bounds__(256) void gemm_out_kernel(
    const short* __restrict__ Ags, const short* __restrict__ Bts,
    float* __restrict__ Cf, const float* __restrict__ bias) {
  __shared__ __align__(16) short As[2 * 128 * 32];
  __shared__ __align__(16) short Bs[2 * 128 * 32];
  const int tid = threadIdx.x;
  const int m0 = blockIdx.x * 128;
  const int n0 = blockIdx.y * 128;

  f32x4 acc[4][4];
#pragma unroll
  for (int mi = 0; mi < 4; ++mi)
#pragma unroll
    for (int ni = 0; ni < 4; ++ni)
#pragma unroll
      for (int r = 0; r < 4; ++r) acc[mi][ni][r] = 0.f;

  gemm_mainloop2(Ags, Bts, m0, n0, As, Bs, acc, tid);

  const int lane = tid & 63;
  const int w = tid >> 6;
  const int wr = (w >> 1) * 64, wc = (w & 1) * 64;
  const int g = lane >> 4, lr = lane & 15;
#pragma unroll
  for (int mi = 0; mi < 4; ++mi)
#pragma unroll
    for (int ni = 0; ni < 4; ++ni)
#pragma unroll
      for (int r = 0; r < 4; ++r) {
        int mg = m0 + wr + mi * 16 + g * 4 + r;
        int ng = n0 + wc + ni * 16 + lr;
        Cf[(size_t)mg * Dm + ng] = acc[mi][ni][r] + bias[ng];
      }
}

// Flash attention, causal, fixed-offset softmax (scores bounded; exp2 safe in
// f32; scale cancels in O=PV/l). Block=(bh, pair): q-tiles pi and 15-pi.
// grid.x = bh so the 8 pair-blocks of one bh share id%8 -> same XCD L2.
// 3-buffer, 2-deep prefetch with counted vmcnt (never 0 mid-loop).
__global__ __launch_bounds__(256) void attn_kernel(
    const short* __restrict__ Qg, const short* __restrict__ Kg,
    const short* __restrict__ Vg, short* __restrict__ Og) {
  __shared__ __align__(16) short Kl[3][64 * 64];
  __shared__ __align__(16) short Vl[3][64 * 64];
  __shared__ __align__(16) short Pl[4][32 * 72];
  const int tid = threadIdx.x;
  const int lane = tid & 63;
  const int w = tid >> 6;
  const int g = lane >> 4;
  const int lr = lane & 15;
  const int bh = blockIdx.x;   // XCD locality: same-bh blocks -> same id%8
  const int pi = blockIdx.y;
  const short* Ks = Kg + ((size_t)bh * NKT << 12);
  const short* Vs = Vg + ((size_t)bh * NKT << 12);
  short* Pw = &Pl[w][0];
  const int b_ = bh >> 4, h_ = bh & 15;

  short8 ones;
#pragma unroll
  for (int j = 0; j < 8; ++j) ones[j] = (short)0x3F80;  // bf16 1.0

  auto stage = [&](int t, int buf) {
#pragma unroll
    for (int i = 0; i < 2; ++i) {
      int ch = w * 2 + i;  // 8 chunks of 1024B per 8KB tile; 4 loads/wave total
      gload16(Ks + ((size_t)t << 12) + ch * 512 + lane * 8, &Kl[buf][ch * 512]);
      gload16(Vs + ((size_t)t << 12) + ch * 512 + lane * 8, &Vl[buf][ch * 512]);
    }
  };

  for (int pass = 0; pass < 2; ++pass) {
    const int qb = pass == 0 ? (15 - pi) : pi;  // heavy pass first
    const int q0 = qb * 128;
    const int qw = q0 + w * 32;
    const short* Qs = Qg + ((size_t)bh * Tm + q0) * HDm;

    short8 qf[2][2];
#pragma unroll
    for (int mi = 0; mi < 2; ++mi)
#pragma unroll
      for (int kk = 0; kk < 2; ++kk)
        qf[mi][kk] = *reinterpret_cast<const short8*>(
            Qs + (w * 32 + mi * 16 + lr) * HDm + kk * 32 + g * 8);

    f32x4 o[2][4], lacc[2];
#pragma unroll
    for (int mi = 0; mi < 2; ++mi)
#pragma unroll
      for (int r = 0; r < 4; ++r) {
        lacc[mi][r] = 0.f;
#pragma unroll
        for (int di = 0; di < 4; ++di) o[mi][di][r] = 0.f;
      }

    const int nt = q0 / 64 + 2;
    stage(0, 0);
    stage(1, 1);
    for (int t = 0; t < nt; ++t) {
      // wait for tile t only; tile t+1's 4 loads stay in flight across barrier
      if (t < nt - 1) asm volatile("s_waitcnt vmcnt(4)" ::: "memory");
      else            asm volatile("s_waitcnt vmcnt(0)" ::: "memory");
      __builtin_amdgcn_s_barrier();
      __builtin_amdgcn_sched_barrier(0);
      if (t + 2 < nt) stage(t + 2, (t + 2) % 3);  // 2 compute phases to land
      const int cur = t % 3;
      const int k0 = t * 64;
      const bool active = (k0 <= qw + 31);
      if (active) {
        // hoisted K fragments (swizzle is an involution on 8-short blocks)
        short8 kf[2][4];
#pragma unroll
        for (int ni = 0; ni < 4; ++ni) {
          int row = ni * 16 + lr;
#pragma unroll
          for (int kk = 0; kk < 2; ++kk)
            kf[kk][ni] = *reinterpret_cast<const short8*>(
                &Kl[cur][row * 64 + ((kk * 32 + g * 8) ^ ((row & 7) << 3))]);
        }
        f32x4 s[2][4];
#pragma unroll
        for (int mi = 0; mi < 2; ++mi)
#pragma unroll
          for (int ni = 0; ni < 4; ++ni) {
            f32x4 acc;
#pragma unroll
            for (int r = 0; r < 4; ++r) acc[r] = 0.f;
            acc = MFMA_BF16(qf[mi][0], kf[0][ni], acc, 0, 0, 0);
            acc = MFMA_BF16(qf[mi][1], kf[1][ni], acc, 0, 0, 0);
            s[mi][ni] = acc;
          }
        if (k0 + 63 > qw) {  // wave-uniform diag branch: apply causal mask
#pragma unroll
          for (int mi = 0; mi < 2; ++mi)
#pragma unroll
            for (int ni = 0; ni < 4; ++ni)
#pragma unroll
              for (int r = 0; r < 4; ++r)
                if (k0 + ni * 16 + lr > qw + mi * 16 + g * 4 + r) s[mi][ni][r] = -1e30f;
        }
        // p = exp2(s); P -> per-wave LDS (XOR-swizzled cols, conflict-free)
#pragma unroll
        for (int mi = 0; mi < 2; ++mi)
#pragma unroll
          for (int ni = 0; ni < 4; ++ni)
#pragma unroll
            for (int r = 0; r < 4; ++r)
              Pw[(mi * 16 + g * 4 + r) * 72 + ((ni * 16 + lr) ^ (g << 4))] =
                  (short)f2bf(fexp2(s[mi][ni][r]));

        // O += P @ V ; l += P @ 1  (V^T in LDS, swizzled cols)
#pragma unroll
        for (int kk = 0; kk < 2; ++kk) {
          short8 pf[2];
#pragma unroll
          for (int mi = 0; mi < 2; ++mi)
            pf[mi] = *reinterpret_cast<const short8*>(
                &Pw[(mi * 16 + lr) * 72 + ((kk * 32 + g * 8) ^ ((lr >> 2) << 4))]);
#pragma unroll
          for (int mi = 0; mi < 2; ++mi)
            lacc[mi] = MFMA_BF16(pf[mi], ones, lacc[mi], 0, 0, 0);
#pragma unroll
          for (int di = 0; di < 4; ++di) {
            int d = di * 16 + lr;
            short8 vf = *reinterpret_cast<const short8*>(
                &Vl[cur][d * 64 + ((kk * 32 + g * 8) ^ ((d & 7) << 3))]);
#pragma unroll
            for (int mi = 0; mi < 2; ++mi)
              o[mi][di] = MFMA_BF16(pf[mi], vf, o[mi][di], 0, 0, 0);
          }
        }
      }
    }
    __syncthreads();  // pass boundary: all reads done before buffers restaged

    // normalize, scatter to (B,T,D) bf16
#pragma unroll
    for (int mi = 0; mi < 2; ++mi)
#pragma unroll
      for (int di = 0; di < 4; ++di)
#pragma unroll
        for (int r = 0; r < 4; ++r) {
          float ov = o[mi][di][r] / lacc[mi][r];
          int qg = q0 + w * 32 + mi * 16 + g * 4 + r;
          int d_ = di * 16 + lr;
          Og[((size_t)b_ * Tm + qg) * Dm + h_ * HDm + d_] = (short)f2bf(ov);
        }
  }
}

extern "C" void kernel_launch(void* const* d_in, const int* in_sizes, int n_in,
                              void* d_out, int out_size, void* d_ws, size_t ws_size,
                              hipStream_t stream) {
  const float* X = (const float*)d_in[0];
  const float* Wq = (const float*)d_in[1];
  const float* Wk = (const float*)d_in[2];
  const float* Wv = (const float*)d_in[3];
  const float* Wo = (const float*)d_in[4];
  const float* bo = (const float*)d_in[5];
  float* out = (float*)d_out;

  char* ws = (char*)d_ws;
  short* Xb = (short*)ws;  ws += (size_t)Mtot * Dm * 2;
  short* Wqt = (short*)ws; ws += (size_t)Dm * Dm * 2;  // [3072][1024] contiguous
  short* Wkt = (short*)ws; ws += (size_t)Dm * Dm * 2;
  short* Wvt = (short*)ws; ws += (size_t)Dm * Dm * 2;
  short* Wot = (short*)ws; ws += (size_t)Dm * Dm * 2;
  short* Qb = (short*)ws;  ws += (size_t)Mtot * Dm * 2;
  short* Kb = (short*)ws;  ws += (size_t)Mtot * Dm * 2;
  short* Vb = (short*)ws;  ws += (size_t)Mtot * Dm * 2;
  short* Ab = (short*)ws;  ws += (size_t)Mtot * Dm * 2;

  cvt_kernel<<<dim3(1024), dim3(256), 0, stream>>>(X, Xb, Mtot * Dm);
  cvt_t_kernel<<<dim3(16, 16, 4), dim3(256), 0, stream>>>(Wq, Wk, Wv, Wo, Wqt, Wkt, Wvt, Wot);

  gemm_qkv_kernel<<<dim3(Mtot / 128, 3 * Dm / 128), 256, 0, stream>>>(
      Xb, Wqt, Qb, Kb, Vb);

  attn_kernel<<<dim3(Bb * NHm, 8), 256, 0, stream>>>(Qb, Kb, Vb, Ab);

  gemm_out_kernel<<<dim3(Mtot / 128, Dm / 128), 256, 0, stream>>>(Ab, Wot, out, bo);
}